// Round 7
// baseline (6138.881 us; speedup 1.0000x reference)
//
#include <hip/hip_runtime.h>

#define Tn 1024
#define Fn 64
#define Un 256
#define Gn 1024
#define THREADS 1024
#define NB 32        // one block per 16-row batch group — ZERO cross-block comms
#define ASB 272      // A_s (h, int8) row stride bytes: 256 + 16 pad (bank-skew)
#define XSW 72       // xs (x, bf16) row stride ushorts: 64 + 8 pad

typedef __attribute__((ext_vector_type(8))) short bf16x8;
typedef __attribute__((ext_vector_type(8))) unsigned short ushort8;
typedef __attribute__((ext_vector_type(4))) float f32x4;
typedef __attribute__((ext_vector_type(4))) int i32x4;

// ws layout (bytes): hdr 4K | Up (i8 Uh, 256K) | Wp (bf16 W, 128K) |
// Su (f32[1024]) | Bb (f32[1024])
#define WS_UP 4096
#define WS_WP (WS_UP + 262144)
#define WS_SU (WS_WP + 131072)
#define WS_BB (WS_SU + 4096)

__device__ __forceinline__ float bf2f(unsigned short u){
  union { unsigned int i; float f; } v; v.i = ((unsigned int)u) << 16; return v.f;
}
__device__ __forceinline__ unsigned short f2bf(float f){
  unsigned int u = __float_as_uint(f);
  u += 0x7FFFu + ((u >> 16) & 1u);
  return (unsigned short)(u >> 16);
}
__device__ __forceinline__ float load_f(const void* p, long idx, int isf32){
  if (isf32) return ((const float*)p)[idx];
  return bf2f(((const unsigned short*)p)[idx]);
}
// v_rcp_f32 instead of IEEE divide (round-6 win, kept).
__device__ __forceinline__ float rcp_f(float x){ return __builtin_amdgcn_rcpf(x); }
__device__ __forceinline__ float sigm(float x){ return rcp_f(1.0f + __expf(-x)); }
__device__ __forceinline__ float tanh_f(float x){ return 2.0f * sigm(2.0f * x) - 1.0f; }

// ---------------------------------------------------------------------------
__global__ void init_k(const void* x, int* wsi){
  int tid = threadIdx.x;
  if (tid < 64){
    int cnt = 0;
    for (int s2 = 0; s2 < 4; ++s2){
      float v = bf2f(((const unsigned short*)x)[tid + 64*s2]);
      if (!(fabsf(v) <= 100.0f)) cnt++;
    }
    for (int off = 32; off > 0; off >>= 1) cnt += __shfl_down(cnt, off);
    if (tid == 0) wsi[0] = (cnt > 32) ? 1 : 0;   // 1 => inputs are fp32
  }
}

// ---------------------------------------------------------------------------
// 16-wave column permutation:
//   z-col = g*256 + wv*16 + l15   (g: gate 0..3, wv: wave 0..15, l15: 0..15)
// Packed fragment index (both Up and Wp):
//   idx = ((((kt*16 + wv)*4 + g)*16 + l15)*4 + q)*8 + j,  k = kt*32 + q*8 + j
// (8-contiguous-K-per-lane B layout — verified by rounds 5/6 passing @0.0039)

// Per-column absmax scales + int8 quantization of Uh (K=256 -> 8 k-tiles).
__global__ void scales_k(const void* Uh, const void* bvec, char* Up,
                         float* Su_c, float* Bb_c, const int* dt){
  int isf32 = *dt;
  int col = blockIdx.x * blockDim.x + threadIdx.x;
  if (col >= 1024) return;
  float su = 1e-20f;
  for (int k = 0; k < 256; ++k)
    su = fmaxf(su, fabsf(load_f(Uh, (long)k*Gn + col, isf32)));
  float r = 127.f / su;
  int g = col >> 8, u = col & 255, wv = u >> 4, l15v = u & 15;
  for (int k = 0; k < 256; ++k){
    int kt = k >> 5, q = (k >> 3) & 3, j = k & 7;
    float v = rintf(load_f(Uh, (long)k*Gn + col, isf32) * r);
    v = fminf(fmaxf(v, -127.f), 127.f);
    Up[(long)(((((kt*16 + wv)*4 + g)*16 + l15v)*4 + q)*8 + j)] = (char)(int)v;
  }
  Su_c[col] = su / (127.f * 127.f);   // dequant: z_h = Su * (sum uq*hq)
  Bb_c[col] = load_f(bvec, col, isf32);
}

// Pack W (K=64 -> 2 bf16 k-tiles) into B-fragment order (streamed from L2).
__global__ void wp_k(const void* W, unsigned short* Wp, const int* dt){
  int isf32 = *dt;
  int gidx = blockIdx.x * blockDim.x + threadIdx.x;   // (((kt2*16+wv)*4+g)*16+l15)*4+q
  if (gidx >= 8192) return;
  int q   = gidx & 3;
  int l15v= (gidx >> 2) & 15;
  int g   = (gidx >> 6) & 3;
  int wv  = (gidx >> 8) & 15;
  int kt2 = gidx >> 12;
  int col = g*256 + wv*16 + l15v;
  unsigned short vals[8];
  #pragma unroll
  for (int j = 0; j < 8; ++j){
    int k = kt2*32 + q*8 + j;
    vals[j] = f2bf(load_f(W, (long)k*Gn + col, isf32));
  }
  *(ushort8*)(Wp + (long)gidx * 8) = *(ushort8*)vals;
}

// ---------------------------------------------------------------------------
// Persistent LSTM, 32 blocks x 1024 threads (16 waves), ONE block per group.
// Round-6 post-mortem: 8-wave version needed ~224 VGPR but allocator landed
// on 128 -> Uh weights were re-fetched from L2 every step with 2 waves/SIMD
// of latency hiding (latency-bound, 10300 cy/step vs ~6400 busy). Fix: 16
// waves x 64 cols each -> wfh[8][4]=64 VGPR, total ~120 live, genuinely fits
// the 128-VGPR/4-waves-per-SIMD bin: weights stay resident AND latency
// hiding doubles. Everything else identical to the verified round-6 numerics.
__global__ __launch_bounds__(THREADS) void lstm_k(
    const void* x, const void* dense_w, const void* dense_b,
    const char* Up, const unsigned short* Wp,
    const float* Su_g, const float* Bb_g, const int* dt, void* out)
{
  __shared__ __align__(16) char A_s[2][16*ASB];          // h, int8, dbuf
  __shared__ __align__(16) unsigned short xs[2][16*XSW]; // x rows, bf16, dbuf
  __shared__ float outv[16];

  const int isf32 = *dt;
  const int tid = threadIdx.x;
  const int wv  = tid >> 6;       // wave 0..15 (owns units wv*16..+16, all gates)
  const int l   = tid & 63;
  const int l15 = l & 15;
  const int q   = l >> 4;
  const int gb  = blockIdx.x;     // batch group: rows gb*16..+16

  // ---- Uh int8 fragments into registers: wfh[kt][g] (64 VGPR) ----
  long wfh[8][4];
  #pragma unroll
  for (int kt = 0; kt < 8; ++kt)
    #pragma unroll
    for (int g = 0; g < 4; ++g)
      wfh[kt][g] = *(const long*)(Up +
          (long)(((((kt*16 + wv)*4 + g)*16 + l15)*4 + q)*8));

  // ---- t-invariant per-thread constants -> registers ----
  float su_r[4], bb_r[4];
  #pragma unroll
  for (int g = 0; g < 4; ++g){
    su_r[g] = Su_g[g*256 + wv*16 + l15];
    bb_r[g] = Bb_g[g*256 + wv*16 + l15];
  }

  // ---- prologue: zero h buffer 0, stage x(0), x(1) ----
  for (int i = tid; i < 16*ASB; i += THREADS) A_s[0][i] = 0;
  for (int tt = 0; tt < 2; ++tt){
    if (tid < 128){
      int m = tid >> 3, seg = tid & 7;
      long src = ((long)(gb*16 + m)*Tn + tt)*Fn + seg*8;
      unsigned short v[8];
      if (isf32){ for (int j = 0; j < 8; ++j) v[j] = f2bf(((const float*)x)[src + j]); }
      else      { *(ushort8*)v = *(const ushort8*)((const unsigned short*)x + src); }
      *(ushort8*)&xs[tt][m*XSW + seg*8] = *(ushort8*)v;
    }
  }
  __syncthreads();

  // ---- zx(0) = x_0 @ W + b (bias folded into acc init) ----
  f32x4 accz[4];
  #pragma unroll
  for (int g = 0; g < 4; ++g)
    accz[g] = (f32x4){bb_r[g], bb_r[g], bb_r[g], bb_r[g]};
  #pragma unroll
  for (int kt2 = 0; kt2 < 2; ++kt2){
    bf16x8 afx = *(const bf16x8*)&xs[0][l15*XSW + kt2*32 + q*8];
    #pragma unroll
    for (int g = 0; g < 4; ++g){
      bf16x8 wfx = *(const bf16x8*)(Wp +
          (long)(((((kt2*16 + wv)*4 + g)*16 + l15)*4 + q)*8));
      accz[g] = __builtin_amdgcn_mfma_f32_16x16x32_bf16(afx, wfx, accz[g], 0, 0, 0);
    }
  }

  float c_st[4] = {0.f, 0.f, 0.f, 0.f};

  for (int t = 0; t < Tn; ++t){
    const int buf = t & 1, nbuf = buf ^ 1;

    // (1) x(t+2) global -> regs (consumed at stage (4))
    unsigned short xv[8];
    if (tid < 128 && (t+2) < Tn){
      int m = tid >> 3, seg = tid & 7;
      long src = ((long)(gb*16 + m)*Tn + (t+2))*Fn + seg*8;
      if (isf32){ for (int j = 0; j < 8; ++j) xv[j] = f2bf(((const float*)x)[src + j]); }
      else      { *(ushort8*)xv = *(const ushort8*)((const unsigned short*)x + src); }
    }

    // (2) int8 h-MFMA (8 kt x 4 gates), weights register-resident
    i32x4 acch[4];
    #pragma unroll
    for (int g = 0; g < 4; ++g) acch[g] = (i32x4){0,0,0,0};
    #pragma unroll
    for (int kt = 0; kt < 8; ++kt){
      long af = *(const long*)&A_s[buf][l15*ASB + kt*32 + q*8];
      #pragma unroll
      for (int g = 0; g < 4; ++g)
        acch[g] = __builtin_amdgcn_mfma_i32_16x16x32_i8(
            af, wfh[kt][g], acch[g], 0, 0, 0);
    }

    // (2b) gates: 4 cells/thread (rows q*4+r, unit wv*16+l15)
    #pragma unroll
    for (int r = 0; r < 4; ++r){
      float zi = su_r[0]*(float)acch[0][r] + accz[0][r];
      float zf = su_r[1]*(float)acch[1][r] + accz[1][r];
      float zg = su_r[2]*(float)acch[2][r] + accz[2][r];
      float zo = su_r[3]*(float)acch[3][r] + accz[3][r];
      float ig = sigm(zi), fg = sigm(zf), gt = tanh_f(zg), og = sigm(zo);
      float cn = fg*c_st[r] + ig*gt;
      c_st[r] = cn;
      float hv = og * tanh_f(cn);
      // h in (-1,1) strictly -> rintf(hv*127) in [-127,127]: no clamp needed
      A_s[nbuf][(q*4 + r)*ASB + wv*16 + l15] = (char)(int)rintf(hv * 127.f);
    }

    // (3) zx(t+1) = x_{t+1} @ W + b — exact bf16, into the freed accz regs
    if (t + 1 < Tn){
      const int p = (t + 1) & 1;
      #pragma unroll
      for (int g = 0; g < 4; ++g)
        accz[g] = (f32x4){bb_r[g], bb_r[g], bb_r[g], bb_r[g]};
      #pragma unroll
      for (int kt2 = 0; kt2 < 2; ++kt2){
        bf16x8 afx = *(const bf16x8*)&xs[p][l15*XSW + kt2*32 + q*8];
        #pragma unroll
        for (int g = 0; g < 4; ++g){
          bf16x8 wfx = *(const bf16x8*)(Wp +
              (long)(((((kt2*16 + wv)*4 + g)*16 + l15)*4 + q)*8));
          accz[g] = __builtin_amdgcn_mfma_f32_16x16x32_bf16(afx, wfx, accz[g], 0, 0, 0);
        }
      }
    }

    // (4) stage x(t+2) into xs[(t+2)&1] (parity-disjoint from (3)'s reads)
    if (tid < 128 && (t+2) < Tn){
      int m = tid >> 3, seg = tid & 7;
      *(ushort8*)&xs[(t+2) & 1][m*XSW + seg*8] = *(ushort8*)xv;
    }
    __syncthreads();   // single barrier: h(t+1) + x(t+2) visible
  }

  // ---- epilogue: attention with s-dim==1 collapses to out = sigm(h_T.dw+db) ----
  if (tid < 512){
    int m = tid >> 5, j = tid & 31;
    float partial = 0.f;
    for (int u = j; u < 256; u += 32)
      partial += (float)(int)((signed char)A_s[0][m*ASB + u]) *
                 load_f(dense_w, u, isf32);
    #pragma unroll
    for (int off = 1; off < 32; off <<= 1) partial += __shfl_xor(partial, off);
    if (j == 0)
      outv[m] = sigm(partial * (1.f/127.f) + load_f(dense_b, 0, isf32));
  }
  __syncthreads();
  for (int mm = 0; mm < 16; ++mm){
    float v = outv[mm];
    long base = (long)(gb*16 + mm) * Tn;
    for (int col2 = tid; col2 < Tn; col2 += THREADS){
      if (isf32) ((float*)out)[base + col2] = v;
      else       ((unsigned short*)out)[base + col2] = f2bf(v);
    }
  }
}

// ---------------------------------------------------------------------------
extern "C" void kernel_launch(void* const* d_in, const int* in_sizes, int n_in,
                              void* d_out, int out_size, void* d_ws, size_t ws_size,
                              hipStream_t stream){
  const void* x  = d_in[0];
  const void* W  = d_in[1];
  const void* Uh = d_in[2];
  const void* b  = d_in[3];
  const void* dw = d_in[4];
  const void* db = d_in[5];

  int* hdr = (int*)d_ws;
  char* Up = (char*)d_ws + WS_UP;
  unsigned short* Wp = (unsigned short*)((char*)d_ws + WS_WP);
  float* Su = (float*)((char*)d_ws + WS_SU);
  float* Bb = (float*)((char*)d_ws + WS_BB);

  init_k<<<1, 64, 0, stream>>>(x, hdr);
  scales_k<<<4, 256, 0, stream>>>(Uh, b, Up, Su, Bb, hdr);
  wp_k<<<32, 256, 0, stream>>>(W, Wp, hdr);
  lstm_k<<<NB, THREADS, 0, stream>>>(x, dw, db, Up, Wp, Su, Bb, hdr, d_out);
}